// Round 1
// baseline (588.662 us; speedup 1.0000x reference)
//
#include <hip/hip_runtime.h>
#include <cmath>

#define Tseq 2048
#define Dm   1024
#define NHd  16
#define HDim 64
#define Mrows 4096   // B*T = 2*2048

typedef _Float16 f16;
typedef _Float16 half8 __attribute__((ext_vector_type(8)));
typedef _Float16 half4 __attribute__((ext_vector_type(4)));
typedef float    floatx4 __attribute__((ext_vector_type(4)));

// ---------------------------------------------------------------- transpose + cast
// W: K x N (fp32, row-major) -> Wt: N x K (f16, row-major)
__global__ __launch_bounds__(256) void transp_f16(const float* __restrict__ W,
                                                  f16* __restrict__ Wt, int K, int N) {
  __shared__ float tile[32][33];
  const int n0 = blockIdx.x * 32, k0 = blockIdx.y * 32;
  const int tx = threadIdx.x & 31, ty = threadIdx.x >> 5;  // ty 0..7
#pragma unroll
  for (int i = 0; i < 32; i += 8)
    tile[ty + i][tx] = W[(size_t)(k0 + ty + i) * N + n0 + tx];
  __syncthreads();
#pragma unroll
  for (int i = 0; i < 32; i += 8)
    Wt[(size_t)(n0 + ty + i) * K + k0 + tx] = (f16)tile[tx][ty + i];
}

// ---------------------------------------------------------------- layernorm -> f16
__global__ __launch_bounds__(256) void ln_f16(const float* __restrict__ x,
                                              const float* __restrict__ g,
                                              const float* __restrict__ bb,
                                              f16* __restrict__ out) {
  const int row = blockIdx.x, t = threadIdx.x;
  const float4 v = ((const float4*)(x + (size_t)row * Dm))[t];
  float s  = v.x + v.y + v.z + v.w;
  float ss = v.x * v.x + v.y * v.y + v.z * v.z + v.w * v.w;
#pragma unroll
  for (int m = 32; m >= 1; m >>= 1) { s += __shfl_xor(s, m); ss += __shfl_xor(ss, m); }
  __shared__ float red[8];
  if ((t & 63) == 0) { red[t >> 6] = s; red[4 + (t >> 6)] = ss; }
  __syncthreads();
  const float S  = red[0] + red[1] + red[2] + red[3];
  const float SS = red[4] + red[5] + red[6] + red[7];
  const float mean = S * (1.0f / Dm);
  const float inv  = rsqrtf(SS * (1.0f / Dm) - mean * mean + 1e-5f);
  const float4 gg = ((const float4*)g)[t];
  const float4 bv = ((const float4*)bb)[t];
  half4 o;
  o.x = (f16)(((v.x - mean) * inv) * gg.x + bv.x);
  o.y = (f16)(((v.y - mean) * inv) * gg.y + bv.y);
  o.z = (f16)(((v.z - mean) * inv) * gg.z + bv.z);
  o.w = (f16)(((v.w - mean) * inv) * gg.w + bv.w);
  *((half4*)(out + (size_t)row * Dm) + t) = o;
}

// ---------------------------------------------------------------- GEMM (f16 MFMA)
// C(MxN) = A(MxK) @ B(KxN), with Bt = B^T (NxK) in f16.
// EPI 0: store fp32 C.  EPI 1: C + bias[col] + resid -> fp32.  EPI 2: gelu(C+bias) -> f16.
template <int EPI>
__global__ __launch_bounds__(256, 2) void gemm_f16(const f16* __restrict__ A,
                                                   const f16* __restrict__ Bt,
                                                   int M, int N, int K,
                                                   const float* __restrict__ bias,
                                                   const float* __restrict__ resid,
                                                   float* __restrict__ Cf,
                                                   f16* __restrict__ Ch) {
  __shared__ f16 As[128 * 32];
  __shared__ f16 Bs[128 * 32];
  const int tid = threadIdx.x;
  const int m0 = blockIdx.y * 128, n0 = blockIdx.x * 128;
  const int w = tid >> 6, l = tid & 63;
  const int wr = (w >> 1) * 64, wc = (w & 1) * 64;
  const int c = l & 15, qq = l >> 4;
  const int smm = tid >> 2;        // 0..63
  const int skk = (tid & 3) * 8;   // 0,8,16,24

  floatx4 acc[4][4] = {};

  const f16* Ab = A + (size_t)(m0 + smm) * K + skk;
  const f16* Bb = Bt + (size_t)(n0 + smm) * K + skk;

  for (int k0 = 0; k0 < K; k0 += 32) {
    __syncthreads();
    *(uint4*)&As[smm * 32 + skk]        = *(const uint4*)(Ab + k0);
    *(uint4*)&As[(smm + 64) * 32 + skk] = *(const uint4*)(Ab + (size_t)64 * K + k0);
    *(uint4*)&Bs[smm * 32 + skk]        = *(const uint4*)(Bb + k0);
    *(uint4*)&Bs[(smm + 64) * 32 + skk] = *(const uint4*)(Bb + (size_t)64 * K + k0);
    __syncthreads();
    half8 af[4], bfr[4];
#pragma unroll
    for (int t = 0; t < 4; ++t) af[t]  = *(const half8*)&As[(wr + t * 16 + c) * 32 + qq * 8];
#pragma unroll
    for (int t = 0; t < 4; ++t) bfr[t] = *(const half8*)&Bs[(wc + t * 16 + c) * 32 + qq * 8];
#pragma unroll
    for (int ti = 0; ti < 4; ++ti)
#pragma unroll
      for (int tj = 0; tj < 4; ++tj)
        acc[ti][tj] = __builtin_amdgcn_mfma_f32_16x16x32_f16(af[ti], bfr[tj], acc[ti][tj], 0, 0, 0);
  }

#pragma unroll
  for (int ti = 0; ti < 4; ++ti)
#pragma unroll
    for (int tj = 0; tj < 4; ++tj)
#pragma unroll
      for (int r = 0; r < 4; ++r) {
        const int row = m0 + wr + ti * 16 + qq * 4 + r;
        const int col = n0 + wc + tj * 16 + c;
        const size_t idx = (size_t)row * N + col;
        float v = acc[ti][tj][r];
        if (EPI == 0) {
          Cf[idx] = v;
        } else if (EPI == 1) {
          Cf[idx] = v + bias[col] + resid[idx];
        } else {
          v += bias[col];
          v = 0.5f * v * (1.0f + erff(v * 0.70710678118654752f));
          Ch[idx] = (f16)v;
        }
      }
}

// ---------------------------------------------------------------- windowed attention
// mask: allowed(i,j) = (j<=i) && (i-j<=128 || j==0 || i==T-1); the i==T-1 clause is
// handled by attn_row (overwrites those rows), so this kernel uses only the first two.
__global__ __launch_bounds__(256, 2) void attn_win(const float* __restrict__ q,
                                                   const float* __restrict__ k,
                                                   const float* __restrict__ v,
                                                   f16* __restrict__ ao) {
  __shared__ float qs[64 * 64];  // [row][d], pre-scaled by 1/8
  __shared__ float ks[64 * 64];  // [d][j]  (transposed)
  __shared__ float vs[64 * 64];  // [j][d]
  __shared__ float ps[64 * 64];  // [row][j], per-wave rows
  const int qt = blockIdx.x;
  const int b = blockIdx.y >> 4, hh = blockIdx.y & 15;
  const int q0 = qt * 64;
  const int tid = threadIdx.x, w = tid >> 6, l = tid & 63;
  const size_t base = ((size_t)b * Tseq) * Dm + hh * HDim;
  const int rr = tid >> 2, cc = (tid & 3) * 16;

  {
    const float* src = q + base + (size_t)(q0 + rr) * Dm + cc;
#pragma unroll
    for (int i = 0; i < 4; ++i) {
      float4 f = ((const float4*)src)[i];
      f.x *= 0.125f; f.y *= 0.125f; f.z *= 0.125f; f.w *= 0.125f;
      *(float4*)&qs[rr * 64 + cc + i * 4] = f;
    }
  }
  float m_run[16], l_run[16], o[16];
#pragma unroll
  for (int r = 0; r < 16; ++r) { m_run[r] = -INFINITY; l_run[r] = 0.f; o[r] = 0.f; }

  int chunks[4]; int nch = 0;
  if (qt > 2) chunks[nch++] = 0;
  for (int ch = (qt - 2 > 0 ? qt - 2 : 0); ch <= qt; ++ch) chunks[nch++] = ch;

  for (int ci = 0; ci < nch; ++ci) {
    const int j0 = chunks[ci] * 64;
    __syncthreads();
    {
      const float* srck = k + base + (size_t)(j0 + rr) * Dm + cc;
      const float* srcv = v + base + (size_t)(j0 + rr) * Dm + cc;
#pragma unroll
      for (int i = 0; i < 4; ++i) {
        const float4 fk = ((const float4*)srck)[i];
        ks[(cc + i * 4 + 0) * 64 + rr] = fk.x;
        ks[(cc + i * 4 + 1) * 64 + rr] = fk.y;
        ks[(cc + i * 4 + 2) * 64 + rr] = fk.z;
        ks[(cc + i * 4 + 3) * 64 + rr] = fk.w;
        const float4 fv = ((const float4*)srcv)[i];
        *(float4*)&vs[rr * 64 + cc + i * 4] = fv;
      }
    }
    __syncthreads();

    float s[16];
#pragma unroll
    for (int r = 0; r < 16; ++r) s[r] = 0.f;
    for (int d4 = 0; d4 < 16; ++d4) {
      const float k0v = ks[(d4 * 4 + 0) * 64 + l];
      const float k1v = ks[(d4 * 4 + 1) * 64 + l];
      const float k2v = ks[(d4 * 4 + 2) * 64 + l];
      const float k3v = ks[(d4 * 4 + 3) * 64 + l];
#pragma unroll
      for (int r = 0; r < 16; ++r) {
        const float4 q4 = *(const float4*)&qs[(w * 16 + r) * 64 + d4 * 4];
        s[r] = fmaf(q4.x, k0v, fmaf(q4.y, k1v, fmaf(q4.z, k2v, fmaf(q4.w, k3v, s[r]))));
      }
    }

    const int j = j0 + l;
#pragma unroll
    for (int r = 0; r < 16; ++r) {
      const int i = q0 + w * 16 + r;
      const bool allowed = (j <= i) && ((i - j) <= 128 || j == 0);
      const float sv = allowed ? s[r] : -INFINITY;
      float mx = sv;
#pragma unroll
      for (int mm = 32; mm >= 1; mm >>= 1) mx = fmaxf(mx, __shfl_xor(mx, mm));
      const float m_new = fmaxf(m_run[r], mx);
      const float p = allowed ? __expf(sv - m_new) : 0.f;
      float sum = p;
#pragma unroll
      for (int mm = 32; mm >= 1; mm >>= 1) sum += __shfl_xor(sum, mm);
      const float alpha = (m_new == -INFINITY) ? 1.f : __expf(m_run[r] - m_new);
      l_run[r] = l_run[r] * alpha + sum;
      o[r] *= alpha;
      m_run[r] = m_new;
      ps[(w * 16 + r) * 64 + l] = p;
    }

    for (int j4 = 0; j4 < 16; ++j4) {
      const float v0 = vs[(j4 * 4 + 0) * 64 + l];
      const float v1 = vs[(j4 * 4 + 1) * 64 + l];
      const float v2 = vs[(j4 * 4 + 2) * 64 + l];
      const float v3 = vs[(j4 * 4 + 3) * 64 + l];
#pragma unroll
      for (int r = 0; r < 16; ++r) {
        const float4 p4 = *(const float4*)&ps[(w * 16 + r) * 64 + j4 * 4];
        o[r] = fmaf(p4.x, v0, fmaf(p4.y, v1, fmaf(p4.z, v2, fmaf(p4.w, v3, o[r]))));
      }
    }
  }
#pragma unroll
  for (int r = 0; r < 16; ++r) {
    const int i = q0 + w * 16 + r;
    ao[((size_t)(b * Tseq + i)) * Dm + hh * HDim + l] = (f16)(o[r] / l_run[r]);
  }
}

// ---------------------------------------------------------------- global row i = T-1
__global__ __launch_bounds__(256) void attn_row(const float* __restrict__ q,
                                                const float* __restrict__ k,
                                                const float* __restrict__ v,
                                                f16* __restrict__ ao) {
  const int b = blockIdx.x >> 4, hh = blockIdx.x & 15;
  const int tid = threadIdx.x;
  const size_t base = ((size_t)b * Tseq) * Dm + hh * HDim;
  __shared__ float qsh[64];
  __shared__ float ps[Tseq];
  __shared__ float wred[4];
  __shared__ float pacc[4][64];
  if (tid < 16) {
    const float4 f = ((const float4*)(q + base + (size_t)(Tseq - 1) * Dm))[tid];
    qsh[tid * 4 + 0] = f.x * 0.125f; qsh[tid * 4 + 1] = f.y * 0.125f;
    qsh[tid * 4 + 2] = f.z * 0.125f; qsh[tid * 4 + 3] = f.w * 0.125f;
  }
  __syncthreads();
  float s[8];
#pragma unroll
  for (int jj = 0; jj < 8; ++jj) {
    const int j = tid * 8 + jj;
    const float* kr = k + base + (size_t)j * Dm;
    float a0 = 0.f;
    for (int d4 = 0; d4 < 16; ++d4) {
      const float4 kv = ((const float4*)kr)[d4];
      a0 += kv.x * qsh[d4 * 4] + kv.y * qsh[d4 * 4 + 1] + kv.z * qsh[d4 * 4 + 2] + kv.w * qsh[d4 * 4 + 3];
    }
    s[jj] = a0;
  }
  float mx = s[0];
#pragma unroll
  for (int jj = 1; jj < 8; ++jj) mx = fmaxf(mx, s[jj]);
#pragma unroll
  for (int mm = 32; mm >= 1; mm >>= 1) mx = fmaxf(mx, __shfl_xor(mx, mm));
  if ((tid & 63) == 0) wred[tid >> 6] = mx;
  __syncthreads();
  const float M = fmaxf(fmaxf(wred[0], wred[1]), fmaxf(wred[2], wred[3]));
  float sum = 0.f;
#pragma unroll
  for (int jj = 0; jj < 8; ++jj) {
    const float p = __expf(s[jj] - M);
    ps[tid * 8 + jj] = p;
    sum += p;
  }
#pragma unroll
  for (int mm = 32; mm >= 1; mm >>= 1) sum += __shfl_xor(sum, mm);
  __syncthreads();  // everyone has read wred (max) before overwrite
  if ((tid & 63) == 0) wred[tid >> 6] = sum;
  __syncthreads();
  const float inv = 1.0f / (wred[0] + wred[1] + wred[2] + wred[3]);
  const int d = tid & 63, part = tid >> 6;
  const float* vb = v + base + d;
  float acc = 0.f;
  for (int j = part * 512; j < part * 512 + 512; ++j)
    acc = fmaf(ps[j], vb[(size_t)j * Dm], acc);
  pacc[part][d] = acc;
  __syncthreads();
  if (tid < 64) {
    const float oo = (pacc[0][tid] + pacc[1][tid] + pacc[2][tid] + pacc[3][tid]) * inv;
    ao[((size_t)(b * Tseq + Tseq - 1)) * Dm + hh * HDim + tid] = (f16)oo;
  }
}

// ---------------------------------------------------------------- launch
extern "C" void kernel_launch(void* const* d_in, const int* in_sizes, int n_in,
                              void* d_out, int out_size, void* d_ws, size_t ws_size,
                              hipStream_t stream) {
  (void)in_sizes; (void)n_in; (void)out_size; (void)ws_size;
  const float* x    = (const float*)d_in[0];
  const float* ln1g = (const float*)d_in[1];
  const float* ln1b = (const float*)d_in[2];
  const float* ln2g = (const float*)d_in[3];
  const float* ln2b = (const float*)d_in[4];
  const float* Wq   = (const float*)d_in[5];
  const float* Wk   = (const float*)d_in[6];
  const float* Wv   = (const float*)d_in[7];
  const float* Wo   = (const float*)d_in[8];
  const float* bo   = (const float*)d_in[9];
  const float* W1   = (const float*)d_in[10];
  const float* b1   = (const float*)d_in[11];
  const float* W2   = (const float*)d_in[12];
  const float* b2   = (const float*)d_in[13];
  float* out = (float*)d_out;

  char* w0 = (char*)d_ws;
  size_t off = 0;
  auto take = [&](size_t bytes) -> char* {
    char* p = w0 + off;
    off += (bytes + 255) & ~(size_t)255;
    return p;
  };
  f16*   WqT   = (f16*)take((size_t)Dm * Dm * 2);
  f16*   WkT   = (f16*)take((size_t)Dm * Dm * 2);
  f16*   WvT   = (f16*)take((size_t)Dm * Dm * 2);
  f16*   WoT   = (f16*)take((size_t)Dm * Dm * 2);
  f16*   W1T   = (f16*)take((size_t)Dm * 4 * Dm * 2);
  f16*   W2T   = (f16*)take((size_t)Dm * 4 * Dm * 2);
  f16*   hF    = (f16*)take((size_t)Mrows * Dm * 2);
  float* qf    = (float*)take((size_t)Mrows * Dm * 4);
  float* kf    = (float*)take((size_t)Mrows * Dm * 4);
  float* vf    = (float*)take((size_t)Mrows * Dm * 4);
  f16*   attnF = (f16*)take((size_t)Mrows * Dm * 2);
  float* x1    = (float*)take((size_t)Mrows * Dm * 4);
  f16*   h2F   = (f16*)take((size_t)Mrows * Dm * 2);
  f16*   ffn1F = (f16*)qf;  // reuse q+k region (32 MB) after attention is done

  const dim3 blk(256);
  transp_f16<<<dim3(Dm / 32, Dm / 32), blk, 0, stream>>>(Wq, WqT, Dm, Dm);
  transp_f16<<<dim3(Dm / 32, Dm / 32), blk, 0, stream>>>(Wk, WkT, Dm, Dm);
  transp_f16<<<dim3(Dm / 32, Dm / 32), blk, 0, stream>>>(Wv, WvT, Dm, Dm);
  transp_f16<<<dim3(Dm / 32, Dm / 32), blk, 0, stream>>>(Wo, WoT, Dm, Dm);
  transp_f16<<<dim3(4 * Dm / 32, Dm / 32), blk, 0, stream>>>(W1, W1T, Dm, 4 * Dm);
  transp_f16<<<dim3(Dm / 32, 4 * Dm / 32), blk, 0, stream>>>(W2, W2T, 4 * Dm, Dm);

  ln_f16<<<Mrows, blk, 0, stream>>>(x, ln1g, ln1b, hF);

  gemm_f16<0><<<dim3(Dm / 128, Mrows / 128), blk, 0, stream>>>(hF, WqT, Mrows, Dm, Dm, nullptr, nullptr, qf, nullptr);
  gemm_f16<0><<<dim3(Dm / 128, Mrows / 128), blk, 0, stream>>>(hF, WkT, Mrows, Dm, Dm, nullptr, nullptr, kf, nullptr);
  gemm_f16<0><<<dim3(Dm / 128, Mrows / 128), blk, 0, stream>>>(hF, WvT, Mrows, Dm, Dm, nullptr, nullptr, vf, nullptr);

  attn_win<<<dim3(Tseq / 64, 2 * NHd), blk, 0, stream>>>(qf, kf, vf, attnF);
  attn_row<<<dim3(2 * NHd), blk, 0, stream>>>(qf, kf, vf, attnF);

  gemm_f16<1><<<dim3(Dm / 128, Mrows / 128), blk, 0, stream>>>(attnF, WoT, Mrows, Dm, Dm, bo, x, x1, nullptr);

  ln_f16<<<Mrows, blk, 0, stream>>>(x1, ln2g, ln2b, h2F);

  gemm_f16<2><<<dim3(4 * Dm / 128, Mrows / 128), blk, 0, stream>>>(h2F, W1T, Mrows, 4 * Dm, Dm, b1, nullptr, nullptr, ffn1F);
  gemm_f16<1><<<dim3(Dm / 128, Mrows / 128), blk, 0, stream>>>(ffn1F, W2T, Mrows, Dm, 4 * Dm, b2, x1, out, nullptr);
}

// Round 3
// 435.878 us; speedup vs baseline: 1.3505x; 1.3505x over previous
//
#include <hip/hip_runtime.h>
#include <cmath>

#define Tseq 2048
#define Dm   1024
#define NHd  16
#define HDim 64
#define Mrows 4096   // B*T = 2*2048
#define PAD  72      // LDS row stride (f16) for attention tiles: 2-way bank alias = free

typedef _Float16 f16;
typedef _Float16 half8 __attribute__((ext_vector_type(8)));
typedef _Float16 half4 __attribute__((ext_vector_type(4)));
typedef float    floatx4 __attribute__((ext_vector_type(4)));

#define ASYNC_COPY16(g, l)                                                       \
  __builtin_amdgcn_global_load_lds((const __attribute__((address_space(1))) void*)(g), \
                                   (__attribute__((address_space(3))) void*)(l), 16, 0, 0)

// ---------------------------------------------------------------- transpose + cast
// W: K x N (fp32, row-major) -> Wt: N x K (f16, row-major)
__global__ __launch_bounds__(256) void transp_f16(const float* __restrict__ W,
                                                  f16* __restrict__ Wt, int K, int N) {
  __shared__ float tile[32][33];
  const int n0 = blockIdx.x * 32, k0 = blockIdx.y * 32;
  const int tx = threadIdx.x & 31, ty = threadIdx.x >> 5;  // ty 0..7
#pragma unroll
  for (int i = 0; i < 32; i += 8)
    tile[ty + i][tx] = W[(size_t)(k0 + ty + i) * N + n0 + tx];
  __syncthreads();
#pragma unroll
  for (int i = 0; i < 32; i += 8)
    Wt[(size_t)(n0 + ty + i) * K + k0 + tx] = (f16)tile[tx][ty + i];
}

// ---------------------------------------------------------------- layernorm -> f16
__global__ __launch_bounds__(256) void ln_f16(const float* __restrict__ x,
                                              const float* __restrict__ g,
                                              const float* __restrict__ bb,
                                              f16* __restrict__ out) {
  const int row = blockIdx.x, t = threadIdx.x;
  const float4 v = ((const float4*)(x + (size_t)row * Dm))[t];
  float s  = v.x + v.y + v.z + v.w;
  float ss = v.x * v.x + v.y * v.y + v.z * v.z + v.w * v.w;
#pragma unroll
  for (int m = 32; m >= 1; m >>= 1) { s += __shfl_xor(s, m); ss += __shfl_xor(ss, m); }
  __shared__ float red[8];
  if ((t & 63) == 0) { red[t >> 6] = s; red[4 + (t >> 6)] = ss; }
  __syncthreads();
  const float S  = red[0] + red[1] + red[2] + red[3];
  const float SS = red[4] + red[5] + red[6] + red[7];
  const float mean = S * (1.0f / Dm);
  const float inv  = rsqrtf(SS * (1.0f / Dm) - mean * mean + 1e-5f);
  const float4 gg = ((const float4*)g)[t];
  const float4 bv = ((const float4*)bb)[t];
  half4 o;
  o.x = (f16)(((v.x - mean) * inv) * gg.x + bv.x);
  o.y = (f16)(((v.y - mean) * inv) * gg.y + bv.y);
  o.z = (f16)(((v.z - mean) * inv) * gg.z + bv.z);
  o.w = (f16)(((v.w - mean) * inv) * gg.w + bv.w);
  *((half4*)(out + (size_t)row * Dm) + t) = o;
}

// ---------------------------------------------------------------- GEMM (f16 MFMA)
// C(MxN) = A(MxK) @ B(KxN), with Bt = B^T (NxK) in f16.  Staging via
// global_load_lds width=16: LDS byte addr == tid*16 == wave_base + lane*16.
// EPI 0: fp32 C.  EPI 1: C+bias[col]+resid -> fp32.  EPI 2: gelu(C+bias) -> f16.
// EPI 3: C -> f16.
template <int EPI>
__global__ __launch_bounds__(256, 2) void gemm_f16(const f16* __restrict__ A,
                                                   const f16* __restrict__ Bt,
                                                   int M, int N, int K,
                                                   const float* __restrict__ bias,
                                                   const float* __restrict__ resid,
                                                   float* __restrict__ Cf,
                                                   f16* __restrict__ Ch) {
  __shared__ f16 As[128 * 32];
  __shared__ f16 Bs[128 * 32];
  const int tid = threadIdx.x;
  const int m0 = blockIdx.y * 128, n0 = blockIdx.x * 128;
  const int w = tid >> 6, l = tid & 63;
  const int wr = (w >> 1) * 64, wc = (w & 1) * 64;
  const int c = l & 15, qq = l >> 4;
  const int smm = tid >> 2;        // 0..63
  const int skk = (tid & 3) * 8;   // 0,8,16,24

  floatx4 acc[4][4] = {};

  const f16* Ab = A + (size_t)(m0 + smm) * K + skk;
  const f16* Bb = Bt + (size_t)(n0 + smm) * K + skk;
  // per-wave LDS bases for the 4 async-copy instructions (f16 elems)
  f16* AsW0 = As + w * 512;
  f16* AsW1 = As + 2048 + w * 512;
  f16* BsW0 = Bs + w * 512;
  f16* BsW1 = Bs + 2048 + w * 512;

  for (int k0 = 0; k0 < K; k0 += 32) {
    __syncthreads();
    ASYNC_COPY16(Ab + k0, AsW0);
    ASYNC_COPY16(Ab + (size_t)64 * K + k0, AsW1);
    ASYNC_COPY16(Bb + k0, BsW0);
    ASYNC_COPY16(Bb + (size_t)64 * K + k0, BsW1);
    __syncthreads();
    half8 af[4], bfr[4];
#pragma unroll
    for (int t = 0; t < 4; ++t) af[t]  = *(const half8*)&As[(wr + t * 16 + c) * 32 + qq * 8];
#pragma unroll
    for (int t = 0; t < 4; ++t) bfr[t] = *(const half8*)&Bs[(wc + t * 16 + c) * 32 + qq * 8];
#pragma unroll
    for (int ti = 0; ti < 4; ++ti)
#pragma unroll
      for (int tj = 0; tj < 4; ++tj)
        acc[ti][tj] = __builtin_amdgcn_mfma_f32_16x16x32_f16(af[ti], bfr[tj], acc[ti][tj], 0, 0, 0);
  }

#pragma unroll
  for (int ti = 0; ti < 4; ++ti)
#pragma unroll
    for (int tj = 0; tj < 4; ++tj)
#pragma unroll
      for (int r = 0; r < 4; ++r) {
        const int row = m0 + wr + ti * 16 + qq * 4 + r;
        const int col = n0 + wc + tj * 16 + c;
        const size_t idx = (size_t)row * N + col;
        float v = acc[ti][tj][r];
        if (EPI == 0) {
          Cf[idx] = v;
        } else if (EPI == 1) {
          Cf[idx] = v + bias[col] + resid[idx];
        } else if (EPI == 2) {
          v += bias[col];
          v = 0.5f * v * (1.0f + erff(v * 0.70710678118654752f));
          Ch[idx] = (f16)v;
        } else {
          Ch[idx] = (f16)v;
        }
      }
}

// ---------------------------------------------------------------- windowed attention (MFMA)
// allowed(i,j) = (j<=i) && (i-j<=128 || j==0); row i==T-1 overwritten by attn_row.
// Per block: 64 q-rows, one (b,h). Wave w owns q-rows w*16..w*16+15.
// QK^T and PV via mfma_f32_16x16x32_f16; P round-trips through LDS (wave-private rows).
__global__ __launch_bounds__(256, 4) void attn_win(const f16* __restrict__ q,
                                                   const f16* __restrict__ k,
                                                   const f16* __restrict__ v,
                                                   f16* __restrict__ ao) {
  __shared__ f16 qs[64 * PAD];   // [i][d]
  __shared__ f16 ks[64 * PAD];   // [j][d]
  __shared__ f16 vts[64 * PAD];  // [d][j]  (transposed)
  __shared__ f16 ps[64 * PAD];   // [i][j]  wave-private row slices
  const int qt = blockIdx.x;
  const int b = blockIdx.y >> 4, hh = blockIdx.y & 15;
  const int q0 = qt * 64;
  const int tid = threadIdx.x, w = tid >> 6, l = tid & 63;
  const int c = l & 15, qq = l >> 4;
  const int wr = w * 16;
  const size_t base = ((size_t)b * Tseq) * Dm + hh * HDim;  // f16 elems
  const int rr = tid >> 2, ss = (tid & 3) * 16;             // staging: row, col-base

  {  // stage Q tile (unscaled; scores scaled by 0.125 post-MFMA)
    const f16* src = q + base + (size_t)(q0 + rr) * Dm + ss;
    *(uint4*)&qs[rr * PAD + ss]     = *(const uint4*)src;
    *(uint4*)&qs[rr * PAD + ss + 8] = *(const uint4*)(src + 8);
  }

  float m_run[4], l_run[4];
  floatx4 oacc[4];  // O: 4 d-tiles; C-layout col=c (d), row=qq*4+r (i)
#pragma unroll
  for (int r = 0; r < 4; ++r) { m_run[r] = -INFINITY; l_run[r] = 0.f; }
#pragma unroll
  for (int td = 0; td < 4; ++td) oacc[td] = (floatx4){0.f, 0.f, 0.f, 0.f};

  int chunks[4]; int nch = 0;
  if (qt > 2) chunks[nch++] = 0;
  for (int ch = (qt - 2 > 0 ? qt - 2 : 0); ch <= qt; ++ch) chunks[nch++] = ch;

  for (int ci = 0; ci < nch; ++ci) {
    const int j0 = chunks[ci] * 64;
    __syncthreads();
    {  // stage K (row-major) and V^T
      const f16* srck = k + base + (size_t)(j0 + rr) * Dm + ss;
      *(uint4*)&ks[rr * PAD + ss]     = *(const uint4*)srck;
      *(uint4*)&ks[rr * PAD + ss + 8] = *(const uint4*)(srck + 8);
      const f16* srcv = v + base + (size_t)(j0 + rr) * Dm + ss;
      uint4 va0 = *(const uint4*)srcv;
      uint4 va1 = *(const uint4*)(srcv + 8);
      const f16* e0 = (const f16*)&va0;
      const f16* e1 = (const f16*)&va1;
#pragma unroll
      for (int i = 0; i < 8; ++i) vts[(ss + i) * PAD + rr] = e0[i];
#pragma unroll
      for (int i = 0; i < 8; ++i) vts[(ss + 8 + i) * PAD + rr] = e1[i];
    }
    __syncthreads();

    // ---- QK^T: S(16x64) per wave
    const half8 a0 = *(const half8*)&qs[(wr + c) * PAD + qq * 8];
    const half8 a1 = *(const half8*)&qs[(wr + c) * PAD + 32 + qq * 8];
    floatx4 sacc[4];
#pragma unroll
    for (int tj = 0; tj < 4; ++tj) {
      const half8 b0 = *(const half8*)&ks[(tj * 16 + c) * PAD + qq * 8];
      const half8 b1 = *(const half8*)&ks[(tj * 16 + c) * PAD + 32 + qq * 8];
      floatx4 s4 = {0.f, 0.f, 0.f, 0.f};
      s4 = __builtin_amdgcn_mfma_f32_16x16x32_f16(a0, b0, s4, 0, 0, 0);
      s4 = __builtin_amdgcn_mfma_f32_16x16x32_f16(a1, b1, s4, 0, 0, 0);
      sacc[tj] = s4;
    }

    // ---- online softmax (rows qq*4+r; j spread over 16 c-lanes x 4 tj regs)
#pragma unroll
    for (int r = 0; r < 4; ++r) {
      const int ii = q0 + wr + qq * 4 + r;
      float sv[4];
      float mx = -INFINITY;
#pragma unroll
      for (int tj = 0; tj < 4; ++tj) {
        const int jj = j0 + tj * 16 + c;
        const bool allowed = (jj <= ii) && ((ii - jj) <= 128 || jj == 0);
        sv[tj] = allowed ? sacc[tj][r] * 0.125f : -INFINITY;
        mx = fmaxf(mx, sv[tj]);
      }
#pragma unroll
      for (int mm = 8; mm >= 1; mm >>= 1) mx = fmaxf(mx, __shfl_xor(mx, mm));
      const float mn = fmaxf(m_run[r], mx);
      const float alpha = (mn == -INFINITY) ? 1.f : __expf(m_run[r] - mn);
      float sum = 0.f;
      float p[4];
#pragma unroll
      for (int tj = 0; tj < 4; ++tj) { p[tj] = __expf(sv[tj] - mn); sum += p[tj]; }
#pragma unroll
      for (int mm = 8; mm >= 1; mm >>= 1) sum += __shfl_xor(sum, mm);
      l_run[r] = l_run[r] * alpha + sum;
      m_run[r] = mn;
#pragma unroll
      for (int td = 0; td < 4; ++td) oacc[td][r] *= alpha;
#pragma unroll
      for (int tj = 0; tj < 4; ++tj)
        ps[(wr + qq * 4 + r) * PAD + tj * 16 + c] = (f16)p[tj];
    }

    // ---- PV: O += P(16x64) * V(64x64)   (wave-private ps rows: no barrier needed)
    const half8 p0 = *(const half8*)&ps[(wr + c) * PAD + qq * 8];
    const half8 p1 = *(const half8*)&ps[(wr + c) * PAD + 32 + qq * 8];
#pragma unroll
    for (int td = 0; td < 4; ++td) {
      const half8 b0 = *(const half8*)&vts[(td * 16 + c) * PAD + qq * 8];
      const half8 b1 = *(const half8*)&vts[(td * 16 + c) * PAD + 32 + qq * 8];
      oacc[td] = __builtin_amdgcn_mfma_f32_16x16x32_f16(p0, b0, oacc[td], 0, 0, 0);
      oacc[td] = __builtin_amdgcn_mfma_f32_16x16x32_f16(p1, b1, oacc[td], 0, 0, 0);
    }
  }

#pragma unroll
  for (int td = 0; td < 4; ++td)
#pragma unroll
    for (int r = 0; r < 4; ++r) {
      const int ii = q0 + wr + qq * 4 + r;
      ao[((size_t)(b * Tseq + ii)) * Dm + hh * HDim + td * 16 + c] =
          (f16)(oacc[td][r] / l_run[r]);
    }
}

// ---------------------------------------------------------------- global row i = T-1
__global__ __launch_bounds__(256) void attn_row(const f16* __restrict__ q,
                                                const f16* __restrict__ k,
                                                const f16* __restrict__ v,
                                                f16* __restrict__ ao) {
  const int b = blockIdx.x >> 4, hh = blockIdx.x & 15;
  const int tid = threadIdx.x;
  const size_t base = ((size_t)b * Tseq) * Dm + hh * HDim;
  __shared__ float qsh[64];
  __shared__ float ps[Tseq];
  __shared__ float wred[4];
  __shared__ float pacc[4][64];
  if (tid < 64) qsh[tid] = (float)q[base + (size_t)(Tseq - 1) * Dm + tid] * 0.125f;
  __syncthreads();
  float s[8];
#pragma unroll
  for (int jj = 0; jj < 8; ++jj) {
    const int j = tid * 8 + jj;
    const f16* kr = k + base + (size_t)j * Dm;
    float a0 = 0.f;
#pragma unroll
    for (int d8 = 0; d8 < 8; ++d8) {
      const half8 kv = *(const half8*)(kr + d8 * 8);
#pragma unroll
      for (int e = 0; e < 8; ++e) a0 = fmaf((float)kv[e], qsh[d8 * 8 + e], a0);
    }
    s[jj] = a0;
  }
  float mx = s[0];
#pragma unroll
  for (int jj = 1; jj < 8; ++jj) mx = fmaxf(mx, s[jj]);
#pragma unroll
  for (int mm = 32; mm >= 1; mm >>= 1) mx = fmaxf(mx, __shfl_xor(mx, mm));
  if ((tid & 63) == 0) wred[tid >> 6] = mx;
  __syncthreads();
  const float M = fmaxf(fmaxf(wred[0], wred[1]), fmaxf(wred[2], wred[3]));
  float sum = 0.f;
#pragma unroll
  for (int jj = 0; jj < 8; ++jj) {
    const float p = __expf(s[jj] - M);
    ps[tid * 8 + jj] = p;
    sum += p;
  }
#pragma unroll
  for (int mm = 32; mm >= 1; mm >>= 1) sum += __shfl_xor(sum, mm);
  __syncthreads();  // all reads of wred (max) done before overwrite
  if ((tid & 63) == 0) wred[tid >> 6] = sum;
  __syncthreads();
  const float inv = 1.0f / (wred[0] + wred[1] + wred[2] + wred[3]);
  const int d = tid & 63, part = tid >> 6;
  const f16* vb = v + base + d;
  float acc = 0.f;
  for (int j = part * 512; j < part * 512 + 512; ++j)
    acc = fmaf(ps[j], (float)vb[(size_t)j * Dm], acc);
  pacc[part][d] = acc;
  __syncthreads();
  if (tid < 64) {
    const float oo = (pacc[0][tid] + pacc[1][tid] + pacc[2][tid] + pacc[3][tid]) * inv;
    ao[((size_t)(b * Tseq + Tseq - 1)) * Dm + hh * HDim + tid] = (f16)oo;
  }
}

// ---------------------------------------------------------------- launch
extern "C" void kernel_launch(void* const* d_in, const int* in_sizes, int n_in,
                              void* d_out, int out_size, void* d_ws, size_t ws_size,
                              hipStream_t stream) {
  (void)in_sizes; (void)n_in; (void)out_size; (void)ws_size;
  const float* x    = (const float*)d_in[0];
  const float* ln1g = (const float*)d_in[1];
  const float* ln1b = (const float*)d_in[2];
  const float* ln2g = (const float*)d_in[3];
  const float* ln2b = (const float*)d_in[4];
  const float* Wq   = (const float*)d_in[5];
  const float* Wk   = (const float*)d_in[6];
  const float* Wv   = (const float*)d_in[7];
  const float* Wo   = (const float*)d_in[8];
  const float* bo   = (const float*)d_in[9];
  const float* W1   = (const float*)d_in[10];
  const float* b1   = (const float*)d_in[11];
  const float* W2   = (const float*)d_in[12];
  const float* b2   = (const float*)d_in[13];
  float* out = (float*)d_out;

  char* w0 = (char*)d_ws;
  size_t off = 0;
  auto take = [&](size_t bytes) -> char* {
    char* p = w0 + off;
    off += (bytes + 255) & ~(size_t)255;
    return p;
  };
  f16*   WqT   = (f16*)take((size_t)Dm * Dm * 2);
  f16*   WkT   = (f16*)take((size_t)Dm * Dm * 2);
  f16*   WvT   = (f16*)take((size_t)Dm * Dm * 2);
  f16*   WoT   = (f16*)take((size_t)Dm * Dm * 2);
  f16*   W1T   = (f16*)take((size_t)Dm * 4 * Dm * 2);
  f16*   W2T   = (f16*)take((size_t)Dm * 4 * Dm * 2);
  f16*   hF    = (f16*)take((size_t)Mrows * Dm * 2);
  f16*   qh    = (f16*)take((size_t)Mrows * Dm * 2);   // qh..attnF: contiguous 32 MiB
  f16*   kh    = (f16*)take((size_t)Mrows * Dm * 2);   // span, reused as ffn1F after
  f16*   vh    = (f16*)take((size_t)Mrows * Dm * 2);   // attention + Wo consume them
  f16*   attnF = (f16*)take((size_t)Mrows * Dm * 2);
  float* x1    = (float*)take((size_t)Mrows * Dm * 4);
  f16*   h2F   = (f16*)take((size_t)Mrows * Dm * 2);
  f16*   ffn1F = qh;  // 4096x4096 f16 = 32 MiB == qh..attnF span

  const dim3 blk(256);
  transp_f16<<<dim3(Dm / 32, Dm / 32), blk, 0, stream>>>(Wq, WqT, Dm, Dm);
  transp_f16<<<dim3(Dm / 32, Dm / 32), blk, 0, stream>>>(Wk, WkT, Dm, Dm);
  transp_f16<<<dim3(Dm / 32, Dm / 32), blk, 0, stream>>>(Wv, WvT, Dm, Dm);
  transp_f16<<<dim3(Dm / 32, Dm / 32), blk, 0, stream>>>(Wo, WoT, Dm, Dm);
  transp_f16<<<dim3(4 * Dm / 32, Dm / 32), blk, 0, stream>>>(W1, W1T, Dm, 4 * Dm);
  transp_f16<<<dim3(Dm / 32, 4 * Dm / 32), blk, 0, stream>>>(W2, W2T, 4 * Dm, Dm);

  ln_f16<<<Mrows, blk, 0, stream>>>(x, ln1g, ln1b, hF);

  gemm_f16<3><<<dim3(Dm / 128, Mrows / 128), blk, 0, stream>>>(hF, WqT, Mrows, Dm, Dm, nullptr, nullptr, nullptr, qh);
  gemm_f16<3><<<dim3(Dm / 128, Mrows / 128), blk, 0, stream>>>(hF, WkT, Mrows, Dm, Dm, nullptr, nullptr, nullptr, kh);
  gemm_f16<3><<<dim3(Dm / 128, Mrows / 128), blk, 0, stream>>>(hF, WvT, Mrows, Dm, Dm, nullptr, nullptr, nullptr, vh);

  attn_win<<<dim3(Tseq / 64, 2 * NHd), blk, 0, stream>>>(qh, kh, vh, attnF);
  attn_row<<<dim3(2 * NHd), blk, 0, stream>>>(qh, kh, vh, attnF);

  gemm_f16<1><<<dim3(Dm / 128, Mrows / 128), blk, 0, stream>>>(attnF, WoT, Mrows, Dm, Dm, bo, x, x1, nullptr);

  ln_f16<<<Mrows, blk, 0, stream>>>(x1, ln2g, ln2b, h2F);

  gemm_f16<2><<<dim3(4 * Dm / 128, Mrows / 128), blk, 0, stream>>>(h2F, W1T, Mrows, 4 * Dm, Dm, b1, nullptr, nullptr, ffn1F);
  gemm_f16<1><<<dim3(Dm / 128, Mrows / 128), blk, 0, stream>>>(ffn1F, W2T, Mrows, Dm, 4 * Dm, b2, x1, out, nullptr);
}

// Round 4
// 423.111 us; speedup vs baseline: 1.3913x; 1.0302x over previous
//
#include <hip/hip_runtime.h>
#include <cmath>

#define Tseq 2048
#define Dm   1024
#define NHd  16
#define HDim 64
#define Mrows 4096   // B*T = 2*2048
#define QS   3072    // packed QKV row stride (f16 elems)
#define PAD  72      // LDS row stride (f16) for attention tiles: 2-way bank alias = free

typedef _Float16 f16;
typedef _Float16 half8 __attribute__((ext_vector_type(8)));
typedef _Float16 half4 __attribute__((ext_vector_type(4)));
typedef float    floatx4 __attribute__((ext_vector_type(4)));

#define ASYNC_COPY16(g, l)                                                       \
  __builtin_amdgcn_global_load_lds((const __attribute__((address_space(1))) void*)(g), \
                                   (__attribute__((address_space(3))) void*)(l), 16, 0, 0)

// ---------------------------------------------------------------- transpose + cast
// W: K x N (fp32, row-major) -> Wt: N x K (f16, row-major)
__global__ __launch_bounds__(256) void transp_f16(const float* __restrict__ W,
                                                  f16* __restrict__ Wt, int K, int N) {
  __shared__ float tile[32][33];
  const int n0 = blockIdx.x * 32, k0 = blockIdx.y * 32;
  const int tx = threadIdx.x & 31, ty = threadIdx.x >> 5;  // ty 0..7
#pragma unroll
  for (int i = 0; i < 32; i += 8)
    tile[ty + i][tx] = W[(size_t)(k0 + ty + i) * N + n0 + tx];
  __syncthreads();
#pragma unroll
  for (int i = 0; i < 32; i += 8)
    Wt[(size_t)(n0 + ty + i) * K + k0 + tx] = (f16)tile[tx][ty + i];
}

// ---------------------------------------------------------------- layernorm -> f16
__global__ __launch_bounds__(256) void ln_f16(const float* __restrict__ x,
                                              const float* __restrict__ g,
                                              const float* __restrict__ bb,
                                              f16* __restrict__ out) {
  const int row = blockIdx.x, t = threadIdx.x;
  const float4 v = ((const float4*)(x + (size_t)row * Dm))[t];
  float s  = v.x + v.y + v.z + v.w;
  float ss = v.x * v.x + v.y * v.y + v.z * v.z + v.w * v.w;
#pragma unroll
  for (int m = 32; m >= 1; m >>= 1) { s += __shfl_xor(s, m); ss += __shfl_xor(ss, m); }
  __shared__ float red[8];
  if ((t & 63) == 0) { red[t >> 6] = s; red[4 + (t >> 6)] = ss; }
  __syncthreads();
  const float S  = red[0] + red[1] + red[2] + red[3];
  const float SS = red[4] + red[5] + red[6] + red[7];
  const float mean = S * (1.0f / Dm);
  const float inv  = rsqrtf(SS * (1.0f / Dm) - mean * mean + 1e-5f);
  const float4 gg = ((const float4*)g)[t];
  const float4 bv = ((const float4*)bb)[t];
  half4 o;
  o.x = (f16)(((v.x - mean) * inv) * gg.x + bv.x);
  o.y = (f16)(((v.y - mean) * inv) * gg.y + bv.y);
  o.z = (f16)(((v.z - mean) * inv) * gg.z + bv.z);
  o.w = (f16)(((v.w - mean) * inv) * gg.w + bv.w);
  *((half4*)(out + (size_t)row * Dm) + t) = o;
}

// ---------------------------------------------------------------- GEMM 128x128 (f16 MFMA)
// C(MxN) = A(MxK) @ B(KxN), Bt = B^T (NxK) f16. global_load_lds width=16 staging.
// EPI 2: gelu(C+bias) -> f16.  EPI 3: C -> f16.
template <int EPI>
__global__ __launch_bounds__(256, 2) void gemm_f16(const f16* __restrict__ A,
                                                   const f16* __restrict__ Bt,
                                                   int M, int N, int K,
                                                   const float* __restrict__ bias,
                                                   f16* __restrict__ Ch) {
  __shared__ f16 As[128 * 32];
  __shared__ f16 Bs[128 * 32];
  const int tid = threadIdx.x;
  const int m0 = blockIdx.y * 128, n0 = blockIdx.x * 128;
  const int w = tid >> 6, l = tid & 63;
  const int wr = (w >> 1) * 64, wc = (w & 1) * 64;
  const int c = l & 15, qq = l >> 4;
  const int smm = tid >> 2;        // 0..63
  const int skk = (tid & 3) * 8;   // 0,8,16,24

  floatx4 acc[4][4] = {};

  const f16* Ab = A + (size_t)(m0 + smm) * K + skk;
  const f16* Bb = Bt + (size_t)(n0 + smm) * K + skk;
  f16* AsW0 = As + w * 512;
  f16* AsW1 = As + 2048 + w * 512;
  f16* BsW0 = Bs + w * 512;
  f16* BsW1 = Bs + 2048 + w * 512;

  for (int k0 = 0; k0 < K; k0 += 32) {
    __syncthreads();
    ASYNC_COPY16(Ab + k0, AsW0);
    ASYNC_COPY16(Ab + (size_t)64 * K + k0, AsW1);
    ASYNC_COPY16(Bb + k0, BsW0);
    ASYNC_COPY16(Bb + (size_t)64 * K + k0, BsW1);
    __syncthreads();
    half8 af[4], bfr[4];
#pragma unroll
    for (int t = 0; t < 4; ++t) af[t]  = *(const half8*)&As[(wr + t * 16 + c) * 32 + qq * 8];
#pragma unroll
    for (int t = 0; t < 4; ++t) bfr[t] = *(const half8*)&Bs[(wc + t * 16 + c) * 32 + qq * 8];
#pragma unroll
    for (int ti = 0; ti < 4; ++ti)
#pragma unroll
      for (int tj = 0; tj < 4; ++tj)
        acc[ti][tj] = __builtin_amdgcn_mfma_f32_16x16x32_f16(af[ti], bfr[tj], acc[ti][tj], 0, 0, 0);
  }

#pragma unroll
  for (int ti = 0; ti < 4; ++ti)
#pragma unroll
    for (int tj = 0; tj < 4; ++tj)
#pragma unroll
      for (int r = 0; r < 4; ++r) {
        const int row = m0 + wr + ti * 16 + qq * 4 + r;
        const int col = n0 + wc + tj * 16 + c;
        const size_t idx = (size_t)row * N + col;
        float v = acc[ti][tj][r];
        if (EPI == 2) {
          v += bias[col];
          v = 0.5f * v * (1.0f + erff(v * 0.70710678118654752f));
          Ch[idx] = (f16)v;
        } else {
          Ch[idx] = (f16)v;
        }
      }
}

// ---------------------------------------------------------------- GEMM 64x128 tile
// For N=1024 GEMMs: grid (N/128, M/64) = 512 blocks -> 2 blocks/CU (vs 1 at 128x128).
// Epilogue: C + bias[col] + resid -> fp32.
__global__ __launch_bounds__(256, 2) void gemm64_f16(const f16* __restrict__ A,
                                                     const f16* __restrict__ Bt,
                                                     int M, int N, int K,
                                                     const float* __restrict__ bias,
                                                     const float* __restrict__ resid,
                                                     float* __restrict__ Cf) {
  __shared__ f16 As[64 * 32];    // 4 KB
  __shared__ f16 Bs[128 * 32];   // 8 KB
  const int tid = threadIdx.x;
  const int m0 = blockIdx.y * 64, n0 = blockIdx.x * 128;
  const int w = tid >> 6, l = tid & 63;
  const int wc = w * 32;         // wave computes 64 rows x 32 cols
  const int c = l & 15, qq = l >> 4;
  const int smm = tid >> 2;      // 0..63
  const int skk = (tid & 3) * 8;

  floatx4 acc[4][2] = {};

  const f16* Ab = A + (size_t)(m0 + smm) * K + skk;
  const f16* Bb = Bt + (size_t)(n0 + smm) * K + skk;
  f16* AsW  = As + w * 512;
  f16* BsW0 = Bs + w * 512;
  f16* BsW1 = Bs + 2048 + w * 512;

  for (int k0 = 0; k0 < K; k0 += 32) {
    __syncthreads();
    ASYNC_COPY16(Ab + k0, AsW);
    ASYNC_COPY16(Bb + k0, BsW0);
    ASYNC_COPY16(Bb + (size_t)64 * K + k0, BsW1);
    __syncthreads();
    half8 af[4], bfr[2];
#pragma unroll
    for (int t = 0; t < 4; ++t) af[t]  = *(const half8*)&As[(t * 16 + c) * 32 + qq * 8];
#pragma unroll
    for (int t = 0; t < 2; ++t) bfr[t] = *(const half8*)&Bs[(wc + t * 16 + c) * 32 + qq * 8];
#pragma unroll
    for (int ti = 0; ti < 4; ++ti)
#pragma unroll
      for (int tj = 0; tj < 2; ++tj)
        acc[ti][tj] = __builtin_amdgcn_mfma_f32_16x16x32_f16(af[ti], bfr[tj], acc[ti][tj], 0, 0, 0);
  }

#pragma unroll
  for (int ti = 0; ti < 4; ++ti)
#pragma unroll
    for (int tj = 0; tj < 2; ++tj)
#pragma unroll
      for (int r = 0; r < 4; ++r) {
        const int row = m0 + ti * 16 + qq * 4 + r;
        const int col = n0 + wc + tj * 16 + c;
        const size_t idx = (size_t)row * N + col;
        Cf[idx] = acc[ti][tj][r] + bias[col] + resid[idx];
      }
}

// ---------------------------------------------------------------- windowed attention (MFMA)
// qkv: packed (Mrows x 3072) f16 — q at col 0, k at 1024, v at 2048 (per head +hh*64).
// allowed(i,j) = (j<=i) && (i-j<=128 || j==0); row i==T-1 overwritten by attn_row.
__global__ __launch_bounds__(256, 4) void attn_win(const f16* __restrict__ qkv,
                                                   f16* __restrict__ ao) {
  __shared__ f16 qs[64 * PAD];   // [i][d]
  __shared__ f16 ks[64 * PAD];   // [j][d]
  __shared__ f16 vts[64 * PAD];  // [d][j]  (transposed)
  __shared__ f16 ps[64 * PAD];   // [i][j]  wave-private row slices
  const int qt = blockIdx.x;
  const int b = blockIdx.y >> 4, hh = blockIdx.y & 15;
  const int q0 = qt * 64;
  const int tid = threadIdx.x, w = tid >> 6, l = tid & 63;
  const int c = l & 15, qq = l >> 4;
  const int wr = w * 16;
  const size_t base = ((size_t)b * Tseq) * QS + hh * HDim;  // f16 elems
  const int rr = tid >> 2, ss = (tid & 3) * 16;             // staging: row, col-base

  {  // stage Q tile (unscaled; scores scaled by 0.125 post-MFMA)
    const f16* src = qkv + base + (size_t)(q0 + rr) * QS + ss;
    *(uint4*)&qs[rr * PAD + ss]     = *(const uint4*)src;
    *(uint4*)&qs[rr * PAD + ss + 8] = *(const uint4*)(src + 8);
  }

  float m_run[4], l_run[4];
  floatx4 oacc[4];  // O: 4 d-tiles; C-layout col=c (d), row=qq*4+r (i)
#pragma unroll
  for (int r = 0; r < 4; ++r) { m_run[r] = -INFINITY; l_run[r] = 0.f; }
#pragma unroll
  for (int td = 0; td < 4; ++td) oacc[td] = (floatx4){0.f, 0.f, 0.f, 0.f};

  int chunks[4]; int nch = 0;
  if (qt > 2) chunks[nch++] = 0;
  for (int ch = (qt - 2 > 0 ? qt - 2 : 0); ch <= qt; ++ch) chunks[nch++] = ch;

  for (int ci = 0; ci < nch; ++ci) {
    const int j0 = chunks[ci] * 64;
    __syncthreads();
    {  // stage K (row-major) and V^T
      const f16* srck = qkv + base + 1024 + (size_t)(j0 + rr) * QS + ss;
      *(uint4*)&ks[rr * PAD + ss]     = *(const uint4*)srck;
      *(uint4*)&ks[rr * PAD + ss + 8] = *(const uint4*)(srck + 8);
      const f16* srcv = qkv + base + 2048 + (size_t)(j0 + rr) * QS + ss;
      uint4 va0 = *(const uint4*)srcv;
      uint4 va1 = *(const uint4*)(srcv + 8);
      const f16* e0 = (const f16*)&va0;
      const f16* e1 = (const f16*)&va1;
#pragma unroll
      for (int i = 0; i < 8; ++i) vts[(ss + i) * PAD + rr] = e0[i];
#pragma unroll
      for (int i = 0; i < 8; ++i) vts[(ss + 8 + i) * PAD + rr] = e1[i];
    }
    __syncthreads();

    // ---- QK^T: S(16x64) per wave
    const half8 a0 = *(const half8*)&qs[(wr + c) * PAD + qq * 8];
    const half8 a1 = *(const half8*)&qs[(wr + c) * PAD + 32 + qq * 8];
    floatx4 sacc[4];
#pragma unroll
    for (int tj = 0; tj < 4; ++tj) {
      const half8 b0 = *(const half8*)&ks[(tj * 16 + c) * PAD + qq * 8];
      const half8 b1 = *(const half8*)&ks[(tj * 16 + c) * PAD + 32 + qq * 8];
      floatx4 s4 = {0.f, 0.f, 0.f, 0.f};
      s4 = __builtin_amdgcn_mfma_f32_16x16x32_f16(a0, b0, s4, 0, 0, 0);
      s4 = __builtin_amdgcn_mfma_f32_16x16x32_f16(a1, b1, s4, 0, 0, 0);
      sacc[tj] = s4;
    }

    // ---- online softmax (rows qq*4+r; j spread over 16 c-lanes x 4 tj regs)
#pragma unroll
    for (int r = 0; r < 4; ++r) {
      const int ii = q0 + wr + qq * 4 + r;
      float sv[4];
      float mx = -INFINITY;
#pragma unroll
      for (int tj = 0; tj < 4; ++tj) {
        const int jj = j0 + tj * 16 + c;
        const bool allowed = (jj <= ii) && ((ii - jj) <= 128 || jj == 0);
        sv[tj] = allowed ? sacc[tj][r] * 0.125f : -INFINITY;
        mx = fmaxf(mx, sv[tj]);
      }
#pragma unroll
      for (int mm = 8; mm >= 1; mm >>= 1) mx = fmaxf(mx, __shfl_xor(mx, mm));
      const float mn = fmaxf(m_run[r], mx);
      const float alpha = (mn == -INFINITY) ? 1.f : __expf(m_run[r] - mn);
      float sum = 0.f;
      float p[4];
#pragma unroll
      for (int tj = 0; tj < 4; ++tj) { p[tj] = __expf(sv[tj] - mn); sum += p[tj]; }
#pragma unroll
      for (int mm = 8; mm >= 1; mm >>= 1) sum += __shfl_xor(sum, mm);
      l_run[r] = l_run[r] * alpha + sum;
      m_run[r] = mn;
#pragma unroll
      for (int td = 0; td < 4; ++td) oacc[td][r] *= alpha;
#pragma unroll
      for (int tj = 0; tj < 4; ++tj)
        ps[(wr + qq * 4 + r) * PAD + tj * 16 + c] = (f16)p[tj];
    }

    // ---- PV: O += P(16x64) * V(64x64)   (wave-private ps rows: no barrier needed)
    const half8 p0 = *(const half8*)&ps[(wr + c) * PAD + qq * 8];
    const half8 p1 = *(const half8*)&ps[(wr + c) * PAD + 32 + qq * 8];
#pragma unroll
    for (int td = 0; td < 4; ++td) {
      const half8 b0 = *(const half8*)&vts[(td * 16 + c) * PAD + qq * 8];
      const half8 b1 = *(const half8*)&vts[(td * 16 + c) * PAD + 32 + qq * 8];
      oacc[td] = __builtin_amdgcn_mfma_f32_16x16x32_f16(p0, b0, oacc[td], 0, 0, 0);
      oacc[td] = __builtin_amdgcn_mfma_f32_16x16x32_f16(p1, b1, oacc[td], 0, 0, 0);
    }
  }

#pragma unroll
  for (int td = 0; td < 4; ++td)
#pragma unroll
    for (int r = 0; r < 4; ++r) {
      const int ii = q0 + wr + qq * 4 + r;
      ao[((size_t)(b * Tseq + ii)) * Dm + hh * HDim + td * 16 + c] =
          (f16)(oacc[td][r] / l_run[r]);
    }
}

// ---------------------------------------------------------------- global row i = T-1
__global__ __launch_bounds__(256) void attn_row(const f16* __restrict__ qkv,
                                                f16* __restrict__ ao) {
  const int b = blockIdx.x >> 4, hh = blockIdx.x & 15;
  const int tid = threadIdx.x;
  const size_t base = ((size_t)b * Tseq) * QS + hh * HDim;
  __shared__ float qsh[64];
  __shared__ float ps[Tseq];
  __shared__ float wred[4];
  __shared__ float pacc[4][64];
  if (tid < 64) qsh[tid] = (float)qkv[base + (size_t)(Tseq - 1) * QS + tid] * 0.125f;
  __syncthreads();
  float s[8];
#pragma unroll
  for (int jj = 0; jj < 8; ++jj) {
    const int j = tid * 8 + jj;
    const f16* kr = qkv + base + 1024 + (size_t)j * QS;
    float a0 = 0.f;
#pragma unroll
    for (int d8 = 0; d8 < 8; ++d8) {
      const half8 kv = *(const half8*)(kr + d8 * 8);
#pragma unroll
      for (int e = 0; e < 8; ++e) a0 = fmaf((float)kv[e], qsh[d8 * 8 + e], a0);
    }
    s[jj] = a0;
  }
  float mx = s[0];
#pragma unroll
  for (int jj = 1; jj < 8; ++jj) mx = fmaxf(mx, s[jj]);
#pragma unroll
  for (int mm = 32; mm >= 1; mm >>= 1) mx = fmaxf(mx, __shfl_xor(mx, mm));
  if ((tid & 63) == 0) wred[tid >> 6] = mx;
  __syncthreads();
  const float M = fmaxf(fmaxf(wred[0], wred[1]), fmaxf(wred[2], wred[3]));
  float sum = 0.f;
#pragma unroll
  for (int jj = 0; jj < 8; ++jj) {
    const float p = __expf(s[jj] - M);
    ps[tid * 8 + jj] = p;
    sum += p;
  }
#pragma unroll
  for (int mm = 32; mm >= 1; mm >>= 1) sum += __shfl_xor(sum, mm);
  __syncthreads();  // all reads of wred (max) done before overwrite
  if ((tid & 63) == 0) wred[tid >> 6] = sum;
  __syncthreads();
  const float inv = 1.0f / (wred[0] + wred[1] + wred[2] + wred[3]);
  const int d = tid & 63, part = tid >> 6;
  const f16* vb = qkv + base + 2048 + d;
  float acc = 0.f;
  for (int j = part * 512; j < part * 512 + 512; ++j)
    acc = fmaf(ps[j], (float)vb[(size_t)j * QS], acc);
  pacc[part][d] = acc;
  __syncthreads();
  if (tid < 64) {
    const float oo = (pacc[0][tid] + pacc[1][tid] + pacc[2][tid] + pacc[3][tid]) * inv;
    ao[((size_t)(b * Tseq + Tseq - 1)) * Dm + hh * HDim + tid] = (f16)oo;
  }
}

// ---------------------------------------------------------------- launch
extern "C" void kernel_launch(void* const* d_in, const int* in_sizes, int n_in,
                              void* d_out, int out_size, void* d_ws, size_t ws_size,
                              hipStream_t stream) {
  (void)in_sizes; (void)n_in; (void)out_size; (void)ws_size;
  const float* x    = (const float*)d_in[0];
  const float* ln1g = (const float*)d_in[1];
  const float* ln1b = (const float*)d_in[2];
  const float* ln2g = (const float*)d_in[3];
  const float* ln2b = (const float*)d_in[4];
  const float* Wq   = (const float*)d_in[5];
  const float* Wk   = (const float*)d_in[6];
  const float* Wv   = (const float*)d_in[7];
  const float* Wo   = (const float*)d_in[8];
  const float* bo   = (const float*)d_in[9];
  const float* W1   = (const float*)d_in[10];
  const float* b1   = (const float*)d_in[11];
  const float* W2   = (const float*)d_in[12];
  const float* b2   = (const float*)d_in[13];
  float* out = (float*)d_out;

  char* w0 = (char*)d_ws;
  size_t off = 0;
  auto take = [&](size_t bytes) -> char* {
    char* p = w0 + off;
    off += (bytes + 255) & ~(size_t)255;
    return p;
  };
  f16*   WqkvT = (f16*)take((size_t)3 * Dm * Dm * 2);      // rows: 0..1023 Wq^T, 1024.. Wk^T, 2048.. Wv^T
  f16*   WoT   = (f16*)take((size_t)Dm * Dm * 2);
  f16*   W1T   = (f16*)take((size_t)Dm * 4 * Dm * 2);
  f16*   W2T   = (f16*)take((size_t)Dm * 4 * Dm * 2);
  f16*   hF    = (f16*)take((size_t)Mrows * Dm * 2);
  f16*   qkvh  = (f16*)take((size_t)Mrows * QS * 2);       // 24 MiB; qkvh..attnF reused as ffn1F
  f16*   attnF = (f16*)take((size_t)Mrows * Dm * 2);       // 8 MiB, contiguous after qkvh
  float* x1    = (float*)take((size_t)Mrows * Dm * 4);
  f16*   h2F   = (f16*)take((size_t)Mrows * Dm * 2);
  f16*   ffn1F = qkvh;  // 4096x4096 f16 = 32 MiB == qkvh(24) + attnF(8) span

  const dim3 blk(256);
  transp_f16<<<dim3(Dm / 32, Dm / 32), blk, 0, stream>>>(Wq, WqkvT, Dm, Dm);
  transp_f16<<<dim3(Dm / 32, Dm / 32), blk, 0, stream>>>(Wk, WqkvT + (size_t)Dm * Dm, Dm, Dm);
  transp_f16<<<dim3(Dm / 32, Dm / 32), blk, 0, stream>>>(Wv, WqkvT + (size_t)2 * Dm * Dm, Dm, Dm);
  transp_f16<<<dim3(Dm / 32, Dm / 32), blk, 0, stream>>>(Wo, WoT, Dm, Dm);
  transp_f16<<<dim3(4 * Dm / 32, Dm / 32), blk, 0, stream>>>(W1, W1T, Dm, 4 * Dm);
  transp_f16<<<dim3(Dm / 32, 4 * Dm / 32), blk, 0, stream>>>(W2, W2T, 4 * Dm, Dm);

  ln_f16<<<Mrows, blk, 0, stream>>>(x, ln1g, ln1b, hF);

  // fused QKV: (4096x1024) @ (1024x3072) -> packed qkvh (stride 3072); 768 blocks
  gemm_f16<3><<<dim3(QS / 128, Mrows / 128), blk, 0, stream>>>(hF, WqkvT, Mrows, QS, Dm, nullptr, qkvh);

  attn_win<<<dim3(Tseq / 64, 2 * NHd), blk, 0, stream>>>(qkvh, attnF);
  attn_row<<<dim3(2 * NHd), blk, 0, stream>>>(qkvh, attnF);

  // Wo: N=1024 -> 64x128 tile, 512 blocks
  gemm64_f16<<<dim3(Dm / 128, Mrows / 64), blk, 0, stream>>>(attnF, WoT, Mrows, Dm, Dm, bo, x, x1);

  ln_f16<<<Mrows, blk, 0, stream>>>(x1, ln2g, ln2b, h2F);

  gemm_f16<2><<<dim3(4 * Dm / 128, Mrows / 128), blk, 0, stream>>>(h2F, W1T, Mrows, 4 * Dm, Dm, b1, ffn1F);
  // W2: N=1024, K=4096 -> 64x128 tile, 512 blocks
  gemm64_f16<<<dim3(Dm / 128, Mrows / 64), blk, 0, stream>>>(ffn1F, W2T, Mrows, Dm, 4 * Dm, b2, x1, out);
}